// Round 3
// baseline (290.207 us; speedup 1.0000x reference)
//
#include <hip/hip_runtime.h>
#include <hip/hip_bf16.h>

// Sparse 3^3 conv x2 + LayerNorm + ReLU + residual. N=400000, C=32, K=27.
// Contract: ALL float inputs are FLOAT32, output f32, nbr int32.
// Workspace: h (bf16, 25.6MB) at d_ws+0; xb (bf16 copy of x) at +25.6MB.
//
// Round-3 (post-mortem r2: structure right -- FETCH 90MB, 82us/pass -- but
// occupancy capped at 2 blocks/CU: 60 VGPR + 32 AGPR = 92 unified regs > 85,
// and 512-thr blocks quantize waves/SIMD in steps of 2. Latency-bound at
// 16 waves/CU):
//  * 32 voxels/wave (2 tiles), grid 782->1563: acc 32->16 regs
//  * register budget <=84 via __launch_bounds__(512,6) -> 3 blocks/CU (LDS
//    53248 allows exactly 3) -> 24 waves/CU
//  * dual-offset index loads: one 64-lane load = indices for TWO offsets
//    (lanes 0-31 offset 2p, lanes 32-63 offset 2p+1); 7-deep static-indexed
//    rotating jn[] gives ~6-iteration prefetch lead on the HBM nbr stream
//  * center (k=13, identity) handled entirely in prologue; its B-frags are
//    transient, not persistent registers

#define NV 400000

typedef __bf16 bf16x8 __attribute__((ext_vector_type(8)));
typedef float  f32x4  __attribute__((ext_vector_type(4)));

union ABu { bf16x8 v; int4 i4; unsigned short us[8]; };

__device__ __forceinline__ unsigned short rb_f2bf(float f) {
    unsigned int u = __float_as_uint(f);
    return (unsigned short)((u + 0x7fffu + ((u >> 16) & 1u)) >> 16);
}

// k index for the 26 non-center offsets (skips k=13, the identity offset)
#define KIDX(kk) ((kk) + ((kk) >= 13 ? 1 : 0))

#define MFMA_BF16 __builtin_amdgcn_mfma_f32_16x16x32_bf16

// x (f32) -> bf16, 8 elems/thread. Exact grid: NV*32/8/512 = 3125 blocks.
__global__ __launch_bounds__(512) void xcvt_kernel(const float* __restrict__ xf,
                                                   unsigned short* __restrict__ xb)
{
    size_t i = ((size_t)blockIdx.x * 512 + threadIdx.x) * 8;
    float4 p0 = *(const float4*)(xf + i);
    float4 p1 = *(const float4*)(xf + i + 4);
    ABu a;
    a.us[0] = rb_f2bf(p0.x); a.us[1] = rb_f2bf(p0.y);
    a.us[2] = rb_f2bf(p0.z); a.us[3] = rb_f2bf(p0.w);
    a.us[4] = rb_f2bf(p1.x); a.us[5] = rb_f2bf(p1.y);
    a.us[6] = rb_f2bf(p1.z); a.us[7] = rb_f2bf(p1.w);
    *(int4*)(xb + i) = a.i4;
}

// Dual-offset neighbor-index load for pair P (offsets kk=2P, 2P+1).
// Lane l<32 loads offset 2P for voxel i0w+l; lane l>=32 loads offset 2P+1.
#define LOADIDX(P)                                                            \
    (okv ? __builtin_nontemporal_load(                                        \
               nbr + (size_t)KIDX(2 * (P)) * NV +                             \
               (size_t)((KIDX(2 * (P) + 1) - KIDX(2 * (P))) * NVhi + vIdx))   \
         : -1)

// Gather pair into named buffer set S (gA or gB) from index register JREG.
#define GATHER_PAIR(S, JREG)                                                  \
    do {                                                                      \
        _Pragma("unroll")                                                     \
        for (int _h = 0; _h < 2; ++_h) {                                      \
            _Pragma("unroll")                                                 \
            for (int _t = 0; _t < 2; ++_t) {                                  \
                int _j = __shfl((JREG), _h * 32 + _t * 16 + n);               \
                g##S[_h][_t] = make_int4(0, 0, 0, 0);                         \
                if (_j >= 0)                                                  \
                    g##S[_h][_t] =                                            \
                        *(const int4*)(gsrc + ((size_t)_j << 5) + qo);        \
            }                                                                 \
        }                                                                     \
    } while (0)

// Consume pair P from buffer set S: 2 offsets x (2 LDS B-frag reads + 4 MFMA).
#define CONSUME_PAIR(P, S)                                                    \
    do {                                                                      \
        _Pragma("unroll")                                                     \
        for (int _h = 0; _h < 2; ++_h) {                                      \
            const int _kk = 2 * (P) + _h;                                     \
            ABu _b0, _b1;                                                     \
            _b0.i4 = *(const int4*)(Bp + _kk * 1024 + lane * 8);              \
            _b1.i4 = *(const int4*)(Bp + _kk * 1024 + 512 + lane * 8);        \
            _Pragma("unroll")                                                 \
            for (int _t = 0; _t < 2; ++_t) {                                  \
                ABu _a; _a.i4 = g##S[_h][_t];                                 \
                acc[_t][0] = MFMA_BF16(_a.v, _b0.v, acc[_t][0], 0, 0, 0);     \
                acc[_t][1] = MFMA_BF16(_a.v, _b1.v, acc[_t][1], 0, 0, 0);     \
            }                                                                 \
        }                                                                     \
    } while (0)

// WRITE_OUT=false: h(bf16) = relu(LN(conv(gsrc)))      (pass 1, gsrc=xb)
// WRITE_OUT=true : out(f32) = relu(LN(conv(gsrc)) + x) (pass 2, gsrc=h)
template <bool WRITE_OUT>
__global__ __launch_bounds__(512, 6) void ResidualBlock_37452114821416_kernel(
    const float* __restrict__ xf,     // x [NV,32] f32 (residual, pass 2)
    const int*   __restrict__ nbr,    // [27,NV]
    const float* __restrict__ Wf,     // [27,32,32] f32
    const float* __restrict__ gf,     // [32]
    const float* __restrict__ bfv,    // [32]
    float*       __restrict__ outf,   // [NV,32] f32
    unsigned short* __restrict__ hbuf,// [NV,32] bf16 scratch (pass-1 dst)
    const unsigned short* __restrict__ gsrc)  // bf16 gather source
{
    // Per-lane MFMA B-fragments for the 26 non-center offsets, packed bf16:
    // Bp[kk*1024 + f*512 + lane*8 + j] = W[k][ci=(lane>>4)*8+j][co=(lane&15)+16f]
    __shared__ __align__(16) unsigned short Bp[26 * 1024];

    const int  lane = threadIdx.x & 63;
    const int  wv   = threadIdx.x >> 6;
    const int  q    = lane >> 4, n = lane & 15;
    const int  i0w  = blockIdx.x * 256 + wv * 32;   // 32 voxels per wave
    const int  vIdx = i0w + (lane & 31);
    const bool okv  = vIdx < NV;
    const int  NVhi = (lane >= 32) ? NV : 0;
    const int  qo   = q * 8;                        // bf16-element offset in row

    // ---- 1) index prefetch, pairs 0..6 (arrive under the LDS fill) ----
    int jn[7];
    #pragma unroll
    for (int p = 0; p < 7; ++p) jn[p] = LOADIDX(p);

    // ---- 2) center self-rows (identity map, coalesced) ----
    int4 cg[2];
    #pragma unroll
    for (int t = 0; t < 2; ++t) {
        int v = i0w + t * 16 + n;
        cg[t] = make_int4(0, 0, 0, 0);
        if (v < NV) cg[t] = *(const int4*)(gsrc + ((size_t)v << 5) + qo);
    }

    // ---- 3) center B-frags (k=13) straight from global f32 (transient) ----
    ABu cb0, cb1;
    #pragma unroll
    for (int j = 0; j < 8; ++j) {
        int ci = (q << 3) + j;
        cb0.us[j] = rb_f2bf(Wf[13 * 1024 + ci * 32 + n]);
        cb1.us[j] = rb_f2bf(Wf[13 * 1024 + ci * 32 + n + 16]);
    }

    // ---- 4) LDS fill (long; hides latencies of 1-3) ----
    for (int e = threadIdx.x; e < 26 * 1024; e += 512) {
        int kk = e >> 10;
        int k  = KIDX(kk);
        int r  = e & 1023;
        int f  = r >> 9;
        int ll = (r >> 3) & 63;
        int j  = r & 7;
        int ci = ((ll >> 4) << 3) + j;
        int co = (ll & 15) + (f << 4);
        Bp[e] = rb_f2bf(Wf[k * 1024 + ci * 32 + co]);
    }
    __syncthreads();

    f32x4 acc[2][2];
    #pragma unroll
    for (int t = 0; t < 2; ++t) {
        acc[t][0] = (f32x4){0.f, 0.f, 0.f, 0.f};
        acc[t][1] = (f32x4){0.f, 0.f, 0.f, 0.f};
    }

    // ---- 5) gathers for pair 0; 6) center MFMA (frees cg/cb) ----
    int4 gA[2][2], gB[2][2];
    GATHER_PAIR(A, jn[0]);
    #pragma unroll
    for (int t = 0; t < 2; ++t) {
        ABu a; a.i4 = cg[t];
        acc[t][0] = MFMA_BF16(a.v, cb0.v, acc[t][0], 0, 0, 0);
        acc[t][1] = MFMA_BF16(a.v, cb1.v, acc[t][1], 0, 0, 0);
    }

    // ---- 7) main pipeline: 13 pairs, fully unrolled, all indices static.
    // iter p: refill jn slot (pair p+7), issue gathers pair p+1 (alternate
    // buffer), consume pair p (waits only on gathers issued at iter p-1).
    #pragma unroll
    for (int p = 0; p < 13; ++p) {
        if (p + 7 < 13) jn[p % 7] = LOADIDX(p + 7);
        if ((p & 1) == 0) {
            if (p + 1 < 13) GATHER_PAIR(B, jn[(p + 1) % 7]);
            CONSUME_PAIR(p, A);
        } else {
            if (p + 1 < 13) GATHER_PAIR(A, jn[(p + 1) % 7]);
            CONSUME_PAIR(p, B);
        }
    }

    // ---- epilogue. C/D layout: cout = lane&15 (+16 frag1), voxel row = q*4+r.
    const float gv0 = gf[n],  gv1 = gf[n + 16];
    const float bv0 = bfv[n], bv1 = bfv[n + 16];
    #pragma unroll
    for (int t = 0; t < 2; ++t) {
        #pragma unroll
        for (int r = 0; r < 4; ++r) {
            float x0 = acc[t][0][r], x1 = acc[t][1][r];
            float s  = x0 + x1;
            float ss = x0 * x0 + x1 * x1;
            #pragma unroll
            for (int mm = 1; mm <= 8; mm <<= 1) {   // LN reduce over 16-lane n-group
                s  += __shfl_xor(s, mm);
                ss += __shfl_xor(ss, mm);
            }
            float mu  = s * (1.f / 32.f);
            float var = ss * (1.f / 32.f) - mu * mu;
            float rs  = rsqrtf(var + 1e-6f);
            int vv = i0w + t * 16 + q * 4 + r;
            if (vv < NV) {
                float y0 = (x0 - mu) * rs * gv0 + bv0;
                float y1 = (x1 - mu) * rs * gv1 + bv1;
                if constexpr (WRITE_OUT) {
                    y0 += xf[(size_t)vv * 32 + n];
                    y1 += xf[(size_t)vv * 32 + n + 16];
                    outf[(size_t)vv * 32 + n]      = fmaxf(y0, 0.f);
                    outf[(size_t)vv * 32 + n + 16] = fmaxf(y1, 0.f);
                } else {
                    hbuf[(size_t)vv * 32 + n]      = rb_f2bf(fmaxf(y0, 0.f));
                    hbuf[(size_t)vv * 32 + n + 16] = rb_f2bf(fmaxf(y1, 0.f));
                }
            }
        }
    }
}

// Fallback pass-1 (no workspace room for xb): round-0-proven serial structure,
// f32 gathers straight from x. Only used when ws_size < 51.2MB.
__global__ __launch_bounds__(512, 4) void pass1_f32_kernel(
    const float* __restrict__ xf, const int* __restrict__ nbr,
    const float* __restrict__ Wf, const float* __restrict__ gf,
    const float* __restrict__ bfv, unsigned short* __restrict__ hbuf)
{
    __shared__ __align__(16) unsigned short Bp[27 * 1024];
    for (int e = threadIdx.x; e < 27 * 1024; e += 512) {
        int k = e >> 10, r = e & 1023, f = r >> 9;
        int ll = (r >> 3) & 63, j = r & 7;
        int ci = ((ll >> 4) << 3) + j, co = (ll & 15) + (f << 4);
        Bp[e] = rb_f2bf(Wf[k * 1024 + ci * 32 + co]);
    }
    __syncthreads();
    const int lane = threadIdx.x & 63, wv = threadIdx.x >> 6;
    const int q = lane >> 4, n = lane & 15;
    const int i0 = blockIdx.x * 512 + wv * 64;
    f32x4 acc[4][2];
    #pragma unroll
    for (int t = 0; t < 4; ++t) { acc[t][0] = (f32x4){0,0,0,0}; acc[t][1] = (f32x4){0,0,0,0}; }
    for (int k = 0; k < 27; ++k) {
        ABu b0, b1;
        b0.i4 = *(const int4*)(Bp + k * 1024 + lane * 8);
        b1.i4 = *(const int4*)(Bp + k * 1024 + 512 + lane * 8);
        const int* nb = nbr + (size_t)k * NV;
        #pragma unroll
        for (int t = 0; t < 4; ++t) {
            int v = i0 + t * 16 + n;
            int jn = (v < NV) ? nb[v] : -1;
            if (__ballot(jn >= 0) == 0ull) continue;
            ABu a; a.i4 = make_int4(0, 0, 0, 0);
            if (jn >= 0) {
                const float* src = xf + (size_t)jn * 32 + q * 8;
                float4 p0 = *(const float4*)(src);
                float4 p1 = *(const float4*)(src + 4);
                a.us[0] = rb_f2bf(p0.x); a.us[1] = rb_f2bf(p0.y);
                a.us[2] = rb_f2bf(p0.z); a.us[3] = rb_f2bf(p0.w);
                a.us[4] = rb_f2bf(p1.x); a.us[5] = rb_f2bf(p1.y);
                a.us[6] = rb_f2bf(p1.z); a.us[7] = rb_f2bf(p1.w);
            }
            acc[t][0] = MFMA_BF16(a.v, b0.v, acc[t][0], 0, 0, 0);
            acc[t][1] = MFMA_BF16(a.v, b1.v, acc[t][1], 0, 0, 0);
        }
    }
    const float gv0 = gf[n], gv1 = gf[n + 16];
    const float bv0 = bfv[n], bv1 = bfv[n + 16];
    #pragma unroll
    for (int t = 0; t < 4; ++t) {
        #pragma unroll
        for (int r = 0; r < 4; ++r) {
            float x0 = acc[t][0][r], x1 = acc[t][1][r];
            float s = x0 + x1, ss = x0 * x0 + x1 * x1;
            #pragma unroll
            for (int mm = 1; mm <= 8; mm <<= 1) { s += __shfl_xor(s, mm); ss += __shfl_xor(ss, mm); }
            float mu = s * (1.f / 32.f);
            float var = ss * (1.f / 32.f) - mu * mu;
            float rs = rsqrtf(var + 1e-6f);
            int vv = i0 + t * 16 + q * 4 + r;
            if (vv < NV) {
                float y0 = (x0 - mu) * rs * gv0 + bv0;
                float y1 = (x1 - mu) * rs * gv1 + bv1;
                hbuf[(size_t)vv * 32 + n]      = rb_f2bf(fmaxf(y0, 0.f));
                hbuf[(size_t)vv * 32 + n + 16] = rb_f2bf(fmaxf(y1, 0.f));
            }
        }
    }
}

extern "C" void kernel_launch(void* const* d_in, const int* in_sizes, int n_in,
                              void* d_out, int out_size, void* d_ws, size_t ws_size,
                              hipStream_t stream)
{
    // setup_inputs() dict order: x, nbr, W1, g1, b1, W2, g2, b2 — all f32 except nbr
    const float* x   = (const float*)d_in[0];
    const int*   nbr = (const int*)d_in[1];
    const float* W1  = (const float*)d_in[2];
    const float* g1  = (const float*)d_in[3];
    const float* b1  = (const float*)d_in[4];
    const float* W2  = (const float*)d_in[5];
    const float* g2  = (const float*)d_in[6];
    const float* b2  = (const float*)d_in[7];
    float* out = (float*)d_out;

    unsigned short* h  = (unsigned short*)d_ws;              // 25.6 MB
    unsigned short* xb = h + (size_t)NV * 32;                // +25.6 MB
    const bool have_xb = ws_size >= (size_t)NV * 32 * 2 * 2; // 51.2 MB needed

    const int nblk = (NV + 255) / 256;   // 1563 blocks x 8 waves x 32 voxels

    if (have_xb) {
        // pass 0: xb = bf16(x)
        xcvt_kernel<<<3125, 512, 0, stream>>>(x, xb);
        // pass 1: h = relu(LN(conv1(xb)))
        ResidualBlock_37452114821416_kernel<false><<<nblk, 512, 0, stream>>>(
            x, nbr, W1, g1, b1, out, h, xb);
    } else {
        pass1_f32_kernel<<<(NV + 511) / 512, 512, 0, stream>>>(
            x, nbr, W1, g1, b1, h);
    }
    // pass 2: out = relu(LN(conv2(h)) + x)
    ResidualBlock_37452114821416_kernel<true><<<nblk, 512, 0, stream>>>(
        x, nbr, W2, g2, b2, out, h, h);

    (void)in_sizes; (void)n_in; (void)out_size;
}